// Round 8
// baseline (145.531 us; speedup 1.0000x reference)
//
#include <hip/hip_runtime.h>

typedef __bf16 bf16_t;
typedef bf16_t bf16x8 __attribute__((ext_vector_type(8)));
typedef bf16_t bf16x4 __attribute__((ext_vector_type(4)));
typedef float f32x4 __attribute__((ext_vector_type(4)));

#define SEQLEN 2048
#define EMB 1024
#define NHEADS 16
#define N3 3072
#define NBATCH 2
#define NEG_INF (-__builtin_inff())
#define SC2 0.18033688011112042f   // 0.125 * log2(e): softmax in exp2 domain

// async global->LDS, 16B per lane. LDS base must be wave-uniform.
__device__ __forceinline__ void async16(bf16_t* lds, const bf16_t* g) {
    __builtin_amdgcn_global_load_lds(
        (const __attribute__((address_space(1))) void*)g,
        (__attribute__((address_space(3))) void*)lds, 16, 0, 0);
}

// ---------------------------------------------------------------------------
// Combined weight transpose + fp32->bf16: W_qkv (48 col-blocks, Q cols
// pre-scaled by SC2) and W_out (16 col-blocks) in one launch.
// ---------------------------------------------------------------------------
__global__ __launch_bounds__(256) void transpose_weights(
    const float* __restrict__ Wqkv, const float* __restrict__ Wout,
    bf16_t* __restrict__ Wqkv_t, bf16_t* __restrict__ Wout_t)
{
    __shared__ float tile[64][65];
    int bx = blockIdx.x;
    const int k0 = blockIdx.y * 64;
    const float* W; bf16_t* Wt; int N; float s;
    if (bx < 48) { W = Wqkv; Wt = Wqkv_t; N = N3;  s = (bx * 64 < EMB) ? SC2 : 1.0f; }
    else         { bx -= 48; W = Wout; Wt = Wout_t; N = EMB; s = 1.0f; }
    const int n0 = bx * 64;
    const int t = threadIdx.x;
    const int nl = t & 63, k4 = t >> 6;
#pragma unroll
    for (int i = 0; i < 16; ++i) {
        int kk = k4 + i * 4;
        tile[kk][nl] = W[(size_t)(k0 + kk) * N + n0 + nl];
    }
    __syncthreads();
    const int kl = t & 63, n4 = t >> 6;
#pragma unroll
    for (int i = 0; i < 16; ++i) {
        int nn = n4 + i * 4;
        Wt[(size_t)(n0 + nn) * EMB + k0 + kl] = (bf16_t)(tile[kl][nn] * s);
    }
}

// ---------------------------------------------------------------------------
// GEMM (m97 structure, 128x128, BK=32): C = A @ Bt^T + bias.
// A_F32: A read as fp32 (X direct), reg-staged + converted + ds_write,
//        prefetched one K-step ahead (named double regs, no dyn indexing);
//        B stays global_load_lds. Requires KT even.
// V_SPLIT (GEMM1): col-blocks >= 2048 write transposed into vt[bh][d][s].
// scale_q: bias cols < EMB multiplied by SC2.
// ---------------------------------------------------------------------------
template<bool OUT_BF16, bool V_SPLIT, bool A_F32>
__global__ __launch_bounds__(256) void gemm_bt_kernel(
    const void* __restrict__ Ap, const bf16_t* __restrict__ Bt,
    const float* __restrict__ bias, void* __restrict__ Cp,
    bf16_t* __restrict__ vt, int scale_q,
    int Mdim, int Ndim, int Kdim)
{
    __shared__ bf16_t As[128 * 32];
    __shared__ bf16_t Bs[128 * 32];
    const int nb = Ndim >> 7;
    const int cpx = gridDim.x >> 3;
    const int bid = (blockIdx.x & 7) * cpx + (blockIdx.x >> 3);
    const int bx = bid % nb, by = bid / nb;
    const int r0 = by << 7, c0 = bx << 7;
    const int t = threadIdx.x, lane = t & 63;
    const int wid = t >> 6;
    const int wm = wid >> 1, wn = wid & 1;
    const int lr = lane & 15, lg = lane >> 4;

    // B staging (global_load_lds): wave w rows [w*32, w*32+32)
    const int glrow = wid * 32 + (lane >> 2);
    const int glcol = (lane & 3) << 3;
    bf16_t* ldsB = &Bs[wid * 1024];
    const bf16_t* gB = &Bt[(size_t)(c0 + glrow) * Kdim + glcol];
    const size_t rowstepB = (size_t)16 * Kdim;

    // A staging
    const int srow = t >> 1, skk = (t & 1) << 4;   // 2 thr/row, 16 elems each
    bf16_t* ldsA = &As[wid * 1024];
    const bf16_t* gA16 = nullptr;
    const float*  gA32 = nullptr;
    if (A_F32) gA32 = &((const float*)Ap)[(size_t)(r0 + srow) * Kdim + skk];
    else       gA16 = &((const bf16_t*)Ap)[(size_t)(r0 + glrow) * Kdim + glcol];

    f32x4 pA0, pA1, pA2, pA3, pB0, pB1, pB2, pB3;
    auto ldAf = [&](int kt, f32x4& a, f32x4& b, f32x4& c, f32x4& d) {
        const float* s = gA32 + kt * 32;
        a = *(const f32x4*)(s);     b = *(const f32x4*)(s + 4);
        c = *(const f32x4*)(s + 8); d = *(const f32x4*)(s + 12);
    };
    auto wrA = [&](f32x4 a, f32x4 b, f32x4 c, f32x4 d) {
        bf16_t bv[16];
#pragma unroll
        for (int j = 0; j < 4; ++j) {
            bv[j]      = (bf16_t)a[j];
            bv[4 + j]  = (bf16_t)b[j];
            bv[8 + j]  = (bf16_t)c[j];
            bv[12 + j] = (bf16_t)d[j];
        }
        *(float4*)&As[srow * 32 + skk]     = *(float4*)&bv[0];
        *(float4*)&As[srow * 32 + skk + 8] = *(float4*)&bv[8];
    };

    f32x4 acc[4][4] = {};
    const int KT = Kdim >> 5;
    if (A_F32) ldAf(0, pA0, pA1, pA2, pA3);

    auto compute = [&]() {
        bf16x8 af[4], bfm[4];
#pragma unroll
        for (int m = 0; m < 4; ++m)
            af[m] = *(const bf16x8*)&As[(wm * 64 + m * 16 + lr) * 32 + lg * 8];
#pragma unroll
        for (int n = 0; n < 4; ++n)
            bfm[n] = *(const bf16x8*)&Bs[(wn * 64 + n * 16 + lr) * 32 + lg * 8];
#pragma unroll
        for (int m = 0; m < 4; ++m)
#pragma unroll
            for (int n = 0; n < 4; ++n)
                acc[m][n] = __builtin_amdgcn_mfma_f32_16x16x32_bf16(
                    af[m], bfm[n], acc[m][n], 0, 0, 0);
    };

    if (A_F32) {
        for (int kt = 0; kt < KT; kt += 2) {
            // even step: write pA, prefetch kt+1 into pB
            {
                const int k0 = kt << 5;
                async16(ldsB,       gB + k0);
                async16(ldsB + 512, gB + k0 + rowstepB);
                wrA(pA0, pA1, pA2, pA3);
                ldAf(kt + 1, pB0, pB1, pB2, pB3);
                __syncthreads();
                compute();
                __syncthreads();
            }
            // odd step: write pB, prefetch kt+2 into pA
            {
                const int k0 = (kt + 1) << 5;
                async16(ldsB,       gB + k0);
                async16(ldsB + 512, gB + k0 + rowstepB);
                wrA(pB0, pB1, pB2, pB3);
                if (kt + 2 < KT) ldAf(kt + 2, pA0, pA1, pA2, pA3);
                __syncthreads();
                compute();
                __syncthreads();
            }
        }
    } else {
        const size_t rowstepA = rowstepB;
        for (int kt = 0; kt < KT; ++kt) {
            const int k0 = kt << 5;
            async16(ldsA,       gA16 + k0);
            async16(ldsA + 512, gA16 + k0 + rowstepA);
            async16(ldsB,       gB + k0);
            async16(ldsB + 512, gB + k0 + rowstepB);
            __syncthreads();
            compute();
            __syncthreads();
        }
    }

    const bool vmode = V_SPLIT && (c0 >= 2 * EMB);
#pragma unroll
    for (int m = 0; m < 4; ++m) {
#pragma unroll
        for (int n = 0; n < 4; ++n) {
            const int col = c0 + wn * 64 + n * 16 + lr;
            float bval = bias[col];
            if (scale_q && col < EMB) bval *= SC2;
            if (vmode) {
                const int h = (col - 2 * EMB) >> 6, dd = col & 63;
                const int bb = r0 >> 11;
                const int sbase = (r0 & (SEQLEN - 1)) + wm * 64 + m * 16 + lg * 4;
                bf16x4 pk;
#pragma unroll
                for (int j = 0; j < 4; ++j) pk[j] = (bf16_t)(acc[m][n][j] + bval);
                *(bf16x4*)&vt[(size_t)((bb * 16 + h) * 64 + dd) * SEQLEN + sbase] = pk;
            } else {
#pragma unroll
                for (int j = 0; j < 4; ++j) {
                    const int row = r0 + wm * 64 + m * 16 + lg * 4 + j;
                    const float v = acc[m][n][j] + bval;
                    if (OUT_BF16)
                        ((bf16_t*)Cp)[(size_t)row * Ndim + col] = (bf16_t)v;
                    else
                        ((float*)Cp)[(size_t)row * Ndim + col] = v;
                }
            }
        }
    }
}

// ---------------------------------------------------------------------------
// Causal flash attention v5 (unchanged from round 6, 47.6 us, 0 conflicts).
// ---------------------------------------------------------------------------
__global__ __launch_bounds__(256, 4) void attn_kernel(
    const bf16_t* __restrict__ qkv, const bf16_t* __restrict__ vt,
    bf16_t* __restrict__ attn_out)
{
    __shared__ bf16_t Kl[2][4096];
    __shared__ bf16_t Vl[2][4096];
    const int d = blockIdx.x;
    const int r = d >> 8;
    const int u = (d >> 3) & 31;
    int qt = (r & 1) ? (31 - u) : u;
    if (r & 2) qt ^= 16;
    const int bh = (d & 7) + (r << 3);
    const int b = bh >> 4, h = bh & 15;
    const int q0 = qt << 6;
    const int t = threadIdx.x, lane = t & 63, wid = t >> 6;
    const int lr = lane & 15, lg = lane >> 4;
    const int sr = t >> 2, sc16 = (t & 3) << 4;

    const int fragb0 = (lr * 128 + lg * 16) ^ ((lr & 7) << 4);
    const int fragb1 = (lr * 128 + 64 + lg * 16) ^ ((lr & 7) << 4);
    const int stb0   = (sr * 128 + sc16 * 2) ^ ((sr & 7) << 4);
    const int stb1   = (sr * 128 + sc16 * 2 + 16) ^ ((sr & 7) << 4);

    const bf16_t* kp = &qkv[(size_t)(b * SEQLEN + sr) * N3 + EMB + h * 64 + sc16];
    const bf16_t* vp = &vt[(size_t)(bh * 64 + sr) * SEQLEN + sc16];
    const size_t kstep = (size_t)64 * N3;

    const int qg = q0 + wid * 16 + lr;
    bf16x8 qa0, qa1;
    {
        const bf16_t* qb = &qkv[(size_t)(b * SEQLEN + qg) * N3 + h * 64];
        qa0 = *(const bf16x8*)&qb[lg * 8];
        qa1 = *(const bf16x8*)&qb[32 + lg * 8];
    }
    bf16x8 ones;
#pragma unroll
    for (int i = 0; i < 8; ++i) ones[i] = (bf16_t)1.0f;

    f32x4 o[4] = {};
    f32x4 ol = {};
    float m_run = NEG_INF;

    auto stK = [&](char* base, float4 a, float4 c) {
        *(float4*)(base + stb0) = a; *(float4*)(base + stb1) = c;
    };
    auto stV = [&](char* base, float4 a, float4 c) {
        float4 w0 = {a.x, a.y, c.x, c.y};
        float4 w1 = {a.z, a.w, c.z, c.w};
        *(float4*)(base + stb0) = w0; *(float4*)(base + stb1) = w1;
    };

    {
        float4 k0 = *(const float4*)kp, k1 = *(const float4*)(kp + 8);
        float4 v0 = *(const float4*)vp, v1 = *(const float4*)(vp + 8);
        stK((char*)Kl[0], k0, k1);
        stV((char*)Vl[0], v0, v1);
    }
    __syncthreads();
    int cur = 0;
    for (int kt = 0; kt <= qt; ++kt) {
        float4 nk0, nk1, nv0, nv1;
        const bool more = (kt < qt);
        if (more) {
            kp += kstep; vp += 64;
            nk0 = *(const float4*)kp; nk1 = *(const float4*)(kp + 8);
            nv0 = *(const float4*)vp; nv1 = *(const float4*)(vp + 8);
        }

        const char* Kc = (const char*)Kl[cur];
        const char* Vc = (const char*)Vl[cur];

        f32x4 sc[4] = {};
        __builtin_amdgcn_s_setprio(1);
#pragma unroll
        for (int n = 0; n < 4; ++n) {
            bf16x8 kb0 = *(const bf16x8*)(Kc + (fragb0 + n * 2048));
            bf16x8 kb1 = *(const bf16x8*)(Kc + (fragb1 + n * 2048));
            sc[n] = __builtin_amdgcn_mfma_f32_16x16x32_bf16(kb0, qa0, sc[n], 0, 0, 0);
            sc[n] = __builtin_amdgcn_mfma_f32_16x16x32_bf16(kb1, qa1, sc[n], 0, 0, 0);
        }
        __builtin_amdgcn_s_setprio(0);

        if (kt == qt) {
#pragma unroll
            for (int n = 0; n < 4; ++n)
#pragma unroll
                for (int j = 0; j < 4; ++j) {
                    const int kg = kt * 64 + n * 16 + lg * 4 + j;
                    sc[n][j] = (kg <= qg) ? sc[n][j] : NEG_INF;
                }
        }
        float mx[4];
#pragma unroll
        for (int n = 0; n < 4; ++n)
            mx[n] = fmaxf(fmaxf(fmaxf(sc[n][0], sc[n][1]), sc[n][2]), sc[n][3]);
        float pmax = fmaxf(fmaxf(fmaxf(mx[0], mx[1]), mx[2]), mx[3]);

        if (__any(pmax > m_run + 8.f)) {
            float pm = fmaxf(pmax, __shfl_xor(pmax, 16));
            pm = fmaxf(pm, __shfl_xor(pm, 32));
            const float mnew = fmaxf(m_run, pm);
            const float alpha = exp2f(m_run - mnew);
            m_run = mnew;
            float al[4];
#pragma unroll
            for (int j = 0; j < 4; ++j) al[j] = __shfl(alpha, lg * 4 + j);
#pragma unroll
            for (int dn = 0; dn < 4; ++dn)
#pragma unroll
                for (int j = 0; j < 4; ++j) o[dn][j] *= al[j];
#pragma unroll
            for (int j = 0; j < 4; ++j) ol[j] *= al[j];
        }

#pragma unroll
        for (int n = 0; n < 4; ++n)
#pragma unroll
            for (int j = 0; j < 4; ++j) sc[n][j] = exp2f(sc[n][j] - m_run);

        unsigned pk00, pk01, pk10, pk11, pk20, pk21, pk30, pk31;
        asm("v_cvt_pk_bf16_f32 %0, %1, %2" : "=v"(pk00) : "v"(sc[0][0]), "v"(sc[0][1]));
        asm("v_cvt_pk_bf16_f32 %0, %1, %2" : "=v"(pk01) : "v"(sc[0][2]), "v"(sc[0][3]));
        asm("v_cvt_pk_bf16_f32 %0, %1, %2" : "=v"(pk10) : "v"(sc[1][0]), "v"(sc[1][1]));
        asm("v_cvt_pk_bf16_f32 %0, %1, %2" : "=v"(pk11) : "v"(sc[1][2]), "v"(sc[1][3]));
        asm("v_cvt_pk_bf16_f32 %0, %1, %2" : "=v"(pk20) : "v"(sc[2][0]), "v"(sc[2][1]));
        asm("v_cvt_pk_bf16_f32 %0, %1, %2" : "=v"(pk21) : "v"(sc[2][2]), "v"(sc[2][3]));
        asm("v_cvt_pk_bf16_f32 %0, %1, %2" : "=v"(pk30) : "v"(sc[3][0]), "v"(sc[3][1]));
        asm("v_cvt_pk_bf16_f32 %0, %1, %2" : "=v"(pk31) : "v"(sc[3][2]), "v"(sc[3][3]));
        asm("v_permlane32_swap_b32 %0, %1" : "+v"(pk00), "+v"(pk10));
        asm("v_permlane32_swap_b32 %0, %1" : "+v"(pk01), "+v"(pk11));
        asm("v_permlane32_swap_b32 %0, %1" : "+v"(pk20), "+v"(pk30));
        asm("v_permlane32_swap_b32 %0, %1" : "+v"(pk21), "+v"(pk31));
        union UW { unsigned w[4]; bf16x8 v; };
        UW ua, ub;
        ua.w[0] = pk00; ua.w[1] = pk01; ua.w[2] = pk10; ua.w[3] = pk11;
        ub.w[0] = pk20; ub.w[1] = pk21; ub.w[2] = pk30; ub.w[3] = pk31;
        const bf16x8 pa0 = ua.v, pa1 = ub.v;

        __builtin_amdgcn_s_setprio(1);
#pragma unroll
        for (int dn = 0; dn < 4; ++dn) {
            bf16x8 vb0 = *(const bf16x8*)(Vc + (fragb0 + dn * 2048));
            bf16x8 vb1 = *(const bf16x8*)(Vc + (fragb1 + dn * 2048));
            o[dn] = __builtin_amdgcn_mfma_f32_16x16x32_bf16(pa0, vb0, o[dn], 0, 0, 0);
            o[dn] = __builtin_amdgcn_mfma_f32_16x16x32_bf16(pa1, vb1, o[dn], 0, 0, 0);
        }
        ol = __builtin_amdgcn_mfma_f32_16x16x32_bf16(pa0, ones, ol, 0, 0, 0);
        ol = __builtin_amdgcn_mfma_f32_16x16x32_bf16(pa1, ones, ol, 0, 0, 0);
        __builtin_amdgcn_s_setprio(0);

        if (more) {
            stK((char*)Kl[cur ^ 1], nk0, nk1);
            stV((char*)Vl[cur ^ 1], nv0, nv1);
        }
        __syncthreads();
        cur ^= 1;
    }

    float li[4];
#pragma unroll
    for (int j = 0; j < 4; ++j) li[j] = 1.0f / ol[j];
#pragma unroll
    for (int dn = 0; dn < 4; ++dn)
#pragma unroll
        for (int j = 0; j < 4; ++j) {
            const int row = b * SEQLEN + q0 + wid * 16 + lg * 4 + j;
            attn_out[(size_t)row * EMB + h * 64 + dn * 16 + lr] =
                (bf16_t)(o[dn][j] * li[j]);
        }
}

// ---------------------------------------------------------------------------
extern "C" void kernel_launch(void* const* d_in, const int* in_sizes, int n_in,
                              void* d_out, int out_size, void* d_ws, size_t ws_size,
                              hipStream_t stream)
{
    const float* X     = (const float*)d_in[0];
    const float* W_qkv = (const float*)d_in[1];
    const float* b_qkv = (const float*)d_in[2];
    const float* W_out = (const float*)d_in[3];
    const float* b_out = (const float*)d_in[4];
    float* out = (float*)d_out;

    char* ws = (char*)d_ws;
    bf16_t* Wqkv_t = (bf16_t*)ws;                           //  6 MB [3072][1024]
    bf16_t* Wout_t = (bf16_t*)(ws + 6u * 1024 * 1024);      //  2 MB [1024][1024]
    bf16_t* qkv    = (bf16_t*)(ws + 8u * 1024 * 1024);      // 24 MB [4096][3072] (V region unused)
    bf16_t* attn   = (bf16_t*)(ws + 32u * 1024 * 1024);     //  8 MB [4096][1024]
    bf16_t* Vt_g   = (bf16_t*)(ws + 48u * 1024 * 1024);     //  8 MB [32][64][2048]

    dim3 blk(256);
    transpose_weights<<<dim3(64, 16), blk, 0, stream>>>(W_qkv, W_out, Wqkv_t, Wout_t);

    // qkv = X(fp32, converted in-kernel) @ W_qkv + b_qkv; V col-blocks -> Vt_g
    gemm_bt_kernel<true, true, true><<<(4096 / 128) * (N3 / 128), blk, 0, stream>>>(
        (const void*)X, Wqkv_t, b_qkv, (void*)qkv, Vt_g, 1, 4096, N3, EMB);

    // causal flash attention -> attn [4096][1024] bf16
    attn_kernel<<<32 * 32, blk, 0, stream>>>(qkv, Vt_g, attn);

    // out = attn @ W_out + b_out  (fp32 out)
    gemm_bt_kernel<false, false, false><<<(4096 / 128) * (EMB / 128), blk, 0, stream>>>(
        (const void*)attn, Wout_t, b_out, (void*)out, nullptr, 0, 4096, EMB, EMB);
}

// Round 9
// 110.854 us; speedup vs baseline: 1.3128x; 1.3128x over previous
//
#include <hip/hip_runtime.h>

typedef __bf16 bf16_t;
typedef bf16_t bf16x8 __attribute__((ext_vector_type(8)));
typedef bf16_t bf16x4 __attribute__((ext_vector_type(4)));
typedef float f32x4 __attribute__((ext_vector_type(4)));

#define SEQLEN 2048
#define EMB 1024
#define NHEADS 16
#define N3 3072
#define NBATCH 2
#define NEG_INF (-__builtin_inff())
#define SC2 0.18033688011112042f   // 0.125 * log2(e): softmax in exp2 domain

// async global->LDS, 16B per lane. LDS base must be wave-uniform.
__device__ __forceinline__ void async16(bf16_t* lds, const bf16_t* g) {
    __builtin_amdgcn_global_load_lds(
        (const __attribute__((address_space(1))) void*)g,
        (__attribute__((address_space(3))) void*)lds, 16, 0, 0);
}

// ---------------------------------------------------------------------------
// Combined weight transpose + fp32->bf16: W_qkv (48 col-blocks, Q cols
// pre-scaled by SC2) and W_out (16 col-blocks) in one launch.
// ---------------------------------------------------------------------------
__global__ __launch_bounds__(256) void transpose_weights(
    const float* __restrict__ Wqkv, const float* __restrict__ Wout,
    bf16_t* __restrict__ Wqkv_t, bf16_t* __restrict__ Wout_t)
{
    __shared__ float tile[64][65];
    int bx = blockIdx.x;
    const int k0 = blockIdx.y * 64;
    const float* W; bf16_t* Wt; int N; float s;
    if (bx < 48) { W = Wqkv; Wt = Wqkv_t; N = N3;  s = (bx * 64 < EMB) ? SC2 : 1.0f; }
    else         { bx -= 48; W = Wout; Wt = Wout_t; N = EMB; s = 1.0f; }
    const int n0 = bx * 64;
    const int t = threadIdx.x;
    const int nl = t & 63, k4 = t >> 6;
#pragma unroll
    for (int i = 0; i < 16; ++i) {
        int kk = k4 + i * 4;
        tile[kk][nl] = W[(size_t)(k0 + kk) * N + n0 + nl];
    }
    __syncthreads();
    const int kl = t & 63, n4 = t >> 6;
#pragma unroll
    for (int i = 0; i < 16; ++i) {
        int nn = n4 + i * 4;
        Wt[(size_t)(n0 + nn) * EMB + k0 + kl] = (bf16_t)(tile[kl][nn] * s);
    }
}

// ---------------------------------------------------------------------------
// fp32 -> bf16 convert (X pre-convert), 8 elems/thread
// ---------------------------------------------------------------------------
__global__ __launch_bounds__(256) void cvt_f32_bf16(
    const float* __restrict__ in, bf16_t* __restrict__ out, int n)
{
    const int i = (blockIdx.x * 256 + threadIdx.x) * 8;
    if (i >= n) return;
    float4 a = *(const float4*)&in[i];
    float4 b = *(const float4*)&in[i + 4];
    bf16_t v[8];
    v[0] = (bf16_t)a.x; v[1] = (bf16_t)a.y; v[2] = (bf16_t)a.z; v[3] = (bf16_t)a.w;
    v[4] = (bf16_t)b.x; v[5] = (bf16_t)b.y; v[6] = (bf16_t)b.z; v[7] = (bf16_t)b.w;
    *(float4*)&out[i] = *(float4*)&v[0];
}

// ---------------------------------------------------------------------------
// GEMM 128x128, BK=64, T2-swizzled: C = A[M][K](bf16) @ Bt[N][K]^T + bias.
// Staging: global_load_lds, linear LDS dest + PRE-SWIZZLED global source
// (srccol = ((l&7)^(l>>3))*8 elems); reads XOR-after-add ^((lr&7)<<4).
// 2 barriers per 32 MFMA (halved vs BK=32). 4 waves (2x2).
// V_SPLIT (GEMM1): col-blocks >= 2048 write transposed into vt[bh][d][s].
// scale_q: bias cols < EMB multiplied by SC2.
// ---------------------------------------------------------------------------
template<bool OUT_BF16, bool V_SPLIT>
__global__ __launch_bounds__(256) void gemm_bt_kernel(
    const bf16_t* __restrict__ A, const bf16_t* __restrict__ Bt,
    const float* __restrict__ bias, void* __restrict__ Cp,
    bf16_t* __restrict__ vt, int scale_q,
    int Mdim, int Ndim, int Kdim)
{
    __shared__ bf16_t As[128 * 64];   // 16 KB
    __shared__ bf16_t Bs[128 * 64];   // 16 KB
    const int nb = Ndim >> 7;
    const int cpx = gridDim.x >> 3;
    const int bid = (blockIdx.x & 7) * cpx + (blockIdx.x >> 3);
    const int bx = bid % nb, by = bid / nb;
    const int r0 = by << 7, c0 = bx << 7;
    const int t = threadIdx.x, lane = t & 63;
    const int wid = t >> 6;
    const int wm = wid >> 1, wn = wid & 1;
    const int lr = lane & 15, lg = lane >> 4;

    // staging: wave w covers rows [w*32, w*32+32), 4 batches of 8 rows each.
    // lane l -> LDS byte (l>>3)*128 + (l&7)*16 (linear); source col pre-swizzled.
    const int glrow = wid * 32 + (lane >> 3);
    const int gsw = ((lane & 7) ^ (lane >> 3)) << 3;     // elems
    const bf16_t* gA = &A[(size_t)(r0 + glrow) * Kdim + gsw];
    const bf16_t* gB = &Bt[(size_t)(c0 + glrow) * Kdim + gsw];
    bf16_t* ldsA = &As[wid * 2048];
    bf16_t* ldsB = &Bs[wid * 2048];
    const size_t row8 = (size_t)8 * Kdim;

    // fragment read bases (byte): XOR applied AFTER all adds (incl. kk*64)
    const int fragb0 = (lr * 128 + lg * 16) ^ ((lr & 7) << 4);
    const int fragb1 = (lr * 128 + 64 + lg * 16) ^ ((lr & 7) << 4);

    f32x4 acc[4][4] = {};
    const int KT = Kdim >> 6;
    for (int kt = 0; kt < KT; ++kt) {
        const bf16_t* a = gA + kt * 64;
        const bf16_t* b = gB + kt * 64;
        async16(ldsA,        a);
        async16(ldsA + 512,  a + row8);
        async16(ldsA + 1024, a + 2 * row8);
        async16(ldsA + 1536, a + 3 * row8);
        async16(ldsB,        b);
        async16(ldsB + 512,  b + row8);
        async16(ldsB + 1024, b + 2 * row8);
        async16(ldsB + 1536, b + 3 * row8);
        __syncthreads();   // drains vmcnt -> LDS tile ready

        const char* Ab = (const char*)As + wm * 8192;   // wm*64 rows * 128 B
        const char* Bb = (const char*)Bs + wn * 8192;
        bf16x8 af[4], bfm[4];
#pragma unroll
        for (int m = 0; m < 4; ++m)
            af[m] = *(const bf16x8*)(Ab + m * 2048 + fragb0);
#pragma unroll
        for (int n = 0; n < 4; ++n)
            bfm[n] = *(const bf16x8*)(Bb + n * 2048 + fragb0);
#pragma unroll
        for (int m = 0; m < 4; ++m)
#pragma unroll
            for (int n = 0; n < 4; ++n)
                acc[m][n] = __builtin_amdgcn_mfma_f32_16x16x32_bf16(
                    af[m], bfm[n], acc[m][n], 0, 0, 0);
#pragma unroll
        for (int m = 0; m < 4; ++m)
            af[m] = *(const bf16x8*)(Ab + m * 2048 + fragb1);
#pragma unroll
        for (int n = 0; n < 4; ++n)
            bfm[n] = *(const bf16x8*)(Bb + n * 2048 + fragb1);
#pragma unroll
        for (int m = 0; m < 4; ++m)
#pragma unroll
            for (int n = 0; n < 4; ++n)
                acc[m][n] = __builtin_amdgcn_mfma_f32_16x16x32_bf16(
                    af[m], bfm[n], acc[m][n], 0, 0, 0);
        __syncthreads();   // reads done before next overwrite
    }

    const bool vmode = V_SPLIT && (c0 >= 2 * EMB);
#pragma unroll
    for (int m = 0; m < 4; ++m) {
#pragma unroll
        for (int n = 0; n < 4; ++n) {
            const int col = c0 + wn * 64 + n * 16 + lr;
            float bval = bias[col];
            if (scale_q && col < EMB) bval *= SC2;
            if (vmode) {
                const int h = (col - 2 * EMB) >> 6, dd = col & 63;
                const int bb = r0 >> 11;
                const int sbase = (r0 & (SEQLEN - 1)) + wm * 64 + m * 16 + lg * 4;
                bf16x4 pk;
#pragma unroll
                for (int j = 0; j < 4; ++j) pk[j] = (bf16_t)(acc[m][n][j] + bval);
                *(bf16x4*)&vt[(size_t)((bb * 16 + h) * 64 + dd) * SEQLEN + sbase] = pk;
            } else {
#pragma unroll
                for (int j = 0; j < 4; ++j) {
                    const int row = r0 + wm * 64 + m * 16 + lg * 4 + j;
                    const float v = acc[m][n][j] + bval;
                    if (OUT_BF16)
                        ((bf16_t*)Cp)[(size_t)row * Ndim + col] = (bf16_t)v;
                    else
                        ((float*)Cp)[(size_t)row * Ndim + col] = v;
                }
            }
        }
    }
}

// ---------------------------------------------------------------------------
// Causal flash attention v5 (round-6 verbatim: 47.6 us, 0 conflicts).
// ---------------------------------------------------------------------------
__global__ __launch_bounds__(256, 4) void attn_kernel(
    const bf16_t* __restrict__ qkv, const bf16_t* __restrict__ vt,
    bf16_t* __restrict__ attn_out)
{
    __shared__ bf16_t Kl[2][4096];
    __shared__ bf16_t Vl[2][4096];
    const int d = blockIdx.x;
    const int r = d >> 8;
    const int u = (d >> 3) & 31;
    int qt = (r & 1) ? (31 - u) : u;
    if (r & 2) qt ^= 16;
    const int bh = (d & 7) + (r << 3);
    const int b = bh >> 4, h = bh & 15;
    const int q0 = qt << 6;
    const int t = threadIdx.x, lane = t & 63, wid = t >> 6;
    const int lr = lane & 15, lg = lane >> 4;
    const int sr = t >> 2, sc16 = (t & 3) << 4;

    const int fragb0 = (lr * 128 + lg * 16) ^ ((lr & 7) << 4);
    const int fragb1 = (lr * 128 + 64 + lg * 16) ^ ((lr & 7) << 4);
    const int stb0   = (sr * 128 + sc16 * 2) ^ ((sr & 7) << 4);
    const int stb1   = (sr * 128 + sc16 * 2 + 16) ^ ((sr & 7) << 4);

    const bf16_t* kp = &qkv[(size_t)(b * SEQLEN + sr) * N3 + EMB + h * 64 + sc16];
    const bf16_t* vp = &vt[(size_t)(bh * 64 + sr) * SEQLEN + sc16];
    const size_t kstep = (size_t)64 * N3;

    const int qg = q0 + wid * 16 + lr;
    bf16x8 qa0, qa1;
    {
        const bf16_t* qb = &qkv[(size_t)(b * SEQLEN + qg) * N3 + h * 64];
        qa0 = *(const bf16x8*)&qb[lg * 8];
        qa1 = *(const bf16x8*)&qb[32 + lg * 8];
    }
    bf16x8 ones;
#pragma unroll
    for (int i = 0; i < 8; ++i) ones[i] = (bf16_t)1.0f;

    f32x4 o[4] = {};
    f32x4 ol = {};
    float m_run = NEG_INF;

    auto stK = [&](char* base, float4 a, float4 c) {
        *(float4*)(base + stb0) = a; *(float4*)(base + stb1) = c;
    };
    auto stV = [&](char* base, float4 a, float4 c) {
        float4 w0 = {a.x, a.y, c.x, c.y};
        float4 w1 = {a.z, a.w, c.z, c.w};
        *(float4*)(base + stb0) = w0; *(float4*)(base + stb1) = w1;
    };

    {
        float4 k0 = *(const float4*)kp, k1 = *(const float4*)(kp + 8);
        float4 v0 = *(const float4*)vp, v1 = *(const float4*)(vp + 8);
        stK((char*)Kl[0], k0, k1);
        stV((char*)Vl[0], v0, v1);
    }
    __syncthreads();
    int cur = 0;
    for (int kt = 0; kt <= qt; ++kt) {
        float4 nk0, nk1, nv0, nv1;
        const bool more = (kt < qt);
        if (more) {
            kp += kstep; vp += 64;
            nk0 = *(const float4*)kp; nk1 = *(const float4*)(kp + 8);
            nv0 = *(const float4*)vp; nv1 = *(const float4*)(vp + 8);
        }

        const char* Kc = (const char*)Kl[cur];
        const char* Vc = (const char*)Vl[cur];

        f32x4 sc[4] = {};
        __builtin_amdgcn_s_setprio(1);
#pragma unroll
        for (int n = 0; n < 4; ++n) {
            bf16x8 kb0 = *(const bf16x8*)(Kc + (fragb0 + n * 2048));
            bf16x8 kb1 = *(const bf16x8*)(Kc + (fragb1 + n * 2048));
            sc[n] = __builtin_amdgcn_mfma_f32_16x16x32_bf16(kb0, qa0, sc[n], 0, 0, 0);
            sc[n] = __builtin_amdgcn_mfma_f32_16x16x32_bf16(kb1, qa1, sc[n], 0, 0, 0);
        }
        __builtin_amdgcn_s_setprio(0);

        if (kt == qt) {
#pragma unroll
            for (int n = 0; n < 4; ++n)
#pragma unroll
                for (int j = 0; j < 4; ++j) {
                    const int kg = kt * 64 + n * 16 + lg * 4 + j;
                    sc[n][j] = (kg <= qg) ? sc[n][j] : NEG_INF;
                }
        }
        float mx[4];
#pragma unroll
        for (int n = 0; n < 4; ++n)
            mx[n] = fmaxf(fmaxf(fmaxf(sc[n][0], sc[n][1]), sc[n][2]), sc[n][3]);
        float pmax = fmaxf(fmaxf(fmaxf(mx[0], mx[1]), mx[2]), mx[3]);

        if (__any(pmax > m_run + 8.f)) {
            float pm = fmaxf(pmax, __shfl_xor(pmax, 16));
            pm = fmaxf(pm, __shfl_xor(pm, 32));
            const float mnew = fmaxf(m_run, pm);
            const float alpha = exp2f(m_run - mnew);
            m_run = mnew;
            float al[4];
#pragma unroll
            for (int j = 0; j < 4; ++j) al[j] = __shfl(alpha, lg * 4 + j);
#pragma unroll
            for (int dn = 0; dn < 4; ++dn)
#pragma unroll
                for (int j = 0; j < 4; ++j) o[dn][j] *= al[j];
#pragma unroll
            for (int j = 0; j < 4; ++j) ol[j] *= al[j];
        }

#pragma unroll
        for (int n = 0; n < 4; ++n)
#pragma unroll
            for (int j = 0; j < 4; ++j) sc[n][j] = exp2f(sc[n][j] - m_run);

        unsigned pk00, pk01, pk10, pk11, pk20, pk21, pk30, pk31;
        asm("v_cvt_pk_bf16_f32 %0, %1, %2" : "=v"(pk00) : "v"(sc[0][0]), "v"(sc[0][1]));
        asm("v_cvt_pk_bf16_f32 %0, %1, %2" : "=v"(pk01) : "v"(sc[0][2]), "v"(sc[0][3]));
        asm("v_cvt_pk_bf16_f32 %0, %1, %2" : "=v"(pk10) : "v"(sc[1][0]), "v"(sc[1][1]));
        asm("v_cvt_pk_bf16_f32 %0, %1, %2" : "=v"(pk11) : "v"(sc[1][2]), "v"(sc[1][3]));
        asm("v_cvt_pk_bf16_f32 %0, %1, %2" : "=v"(pk20) : "v"(sc[2][0]), "v"(sc[2][1]));
        asm("v_cvt_pk_bf16_f32 %0, %1, %2" : "=v"(pk21) : "v"(sc[2][2]), "v"(sc[2][3]));
        asm("v_cvt_pk_bf16_f32 %0, %1, %2" : "=v"(pk30) : "v"(sc[3][0]), "v"(sc[3][1]));
        asm("v_cvt_pk_bf16_f32 %0, %1, %2" : "=v"(pk31) : "v"(sc[3][2]), "v"(sc[3][3]));
        asm("v_permlane32_swap_b32 %0, %1" : "+v"(pk00), "+v"(pk10));
        asm("v_permlane32_swap_b32 %0, %1" : "+v"(pk01), "+v"(pk11));
        asm("v_permlane32_swap_b32 %0, %1" : "+v"(pk20), "+v"(pk30));
        asm("v_permlane32_swap_b32 %0, %1" : "+v"(pk21), "+v"(pk31));
        union UW { unsigned w[4]; bf16x8 v; };
        UW ua, ub;
        ua.w[0] = pk00; ua.w[1] = pk01; ua.w[2] = pk10; ua.w[3] = pk11;
        ub.w[0] = pk20; ub.w[1] = pk21; ub.w[2] = pk30; ub.w[3] = pk31;
        const bf16x8 pa0 = ua.v, pa1 = ub.v;

        __builtin_amdgcn_s_setprio(1);
#pragma unroll
        for (int dn = 0; dn < 4; ++dn) {
            bf16x8 vb0 = *(const bf16x8*)(Vc + (fragb0 + dn * 2048));
            bf16x8 vb1 = *(const bf16x8*)(Vc + (fragb1 + dn * 2048));
            o[dn] = __builtin_amdgcn_mfma_f32_16x16x32_bf16(pa0, vb0, o[dn], 0, 0, 0);
            o[dn] = __builtin_amdgcn_mfma_f32_16x16x32_bf16(pa1, vb1, o[dn], 0, 0, 0);
        }
        ol = __builtin_amdgcn_mfma_f32_16x16x32_bf16(pa0, ones, ol, 0, 0, 0);
        ol = __builtin_amdgcn_mfma_f32_16x16x32_bf16(pa1, ones, ol, 0, 0, 0);
        __builtin_amdgcn_s_setprio(0);

        if (more) {
            stK((char*)Kl[cur ^ 1], nk0, nk1);
            stV((char*)Vl[cur ^ 1], nv0, nv1);
        }
        __syncthreads();
        cur ^= 1;
    }

    float li[4];
#pragma unroll
    for (int j = 0; j < 4; ++j) li[j] = 1.0f / ol[j];
#pragma unroll
    for (int dn = 0; dn < 4; ++dn)
#pragma unroll
        for (int j = 0; j < 4; ++j) {
            const int row = b * SEQLEN + q0 + wid * 16 + lg * 4 + j;
            attn_out[(size_t)row * EMB + h * 64 + dn * 16 + lr] =
                (bf16_t)(o[dn][j] * li[j]);
        }
}

// ---------------------------------------------------------------------------
extern "C" void kernel_launch(void* const* d_in, const int* in_sizes, int n_in,
                              void* d_out, int out_size, void* d_ws, size_t ws_size,
                              hipStream_t stream)
{
    const float* X     = (const float*)d_in[0];
    const float* W_qkv = (const float*)d_in[1];
    const float* b_qkv = (const float*)d_in[2];
    const float* W_out = (const float*)d_in[3];
    const float* b_out = (const float*)d_in[4];
    float* out = (float*)d_out;

    char* ws = (char*)d_ws;
    bf16_t* Wqkv_t = (bf16_t*)ws;                           //  6 MB [3072][1024]
    bf16_t* Wout_t = (bf16_t*)(ws + 6u * 1024 * 1024);      //  2 MB [1024][1024]
    bf16_t* qkv    = (bf16_t*)(ws + 8u * 1024 * 1024);      // 24 MB [4096][3072] (V region unused)
    bf16_t* attn   = (bf16_t*)(ws + 32u * 1024 * 1024);     //  8 MB [4096][1024]
    bf16_t* Xb     = (bf16_t*)(ws + 40u * 1024 * 1024);     //  8 MB [4096][1024]
    bf16_t* Vt_g   = (bf16_t*)(ws + 48u * 1024 * 1024);     //  8 MB [32][64][2048]

    dim3 blk(256);
    transpose_weights<<<dim3(64, 16), blk, 0, stream>>>(W_qkv, W_out, Wqkv_t, Wout_t);
    cvt_f32_bf16<<<4096 * 1024 / (256 * 8), blk, 0, stream>>>(X, Xb, 4096 * 1024);

    // qkv = Xb @ W_qkv + b_qkv; V col-blocks written transposed into Vt_g
    gemm_bt_kernel<true, true><<<(4096 / 128) * (N3 / 128), blk, 0, stream>>>(
        Xb, Wqkv_t, b_qkv, (void*)qkv, Vt_g, 1, 4096, N3, EMB);

    // causal flash attention -> attn [4096][1024] bf16
    attn_kernel<<<32 * 32, blk, 0, stream>>>(qkv, Vt_g, attn);

    // out = attn @ W_out + b_out  (fp32 out)
    gemm_bt_kernel<false, false><<<(4096 / 128) * (EMB / 128), blk, 0, stream>>>(
        attn, Wout_t, b_out, (void*)out, nullptr, 0, 4096, EMB, EMB);
}